// Round 5
// baseline (319.271 us; speedup 1.0000x reference)
//
#include <hip/hip_runtime.h>
#include <hip/hip_bf16.h>

#define T_TOK 2048
#define H_DIM 1024
#define E_N   8
#define I_DIM 2048

#define NT_MAX 40         // sum ceil(cnt_e/128) <= 4096/128 + 7 = 39
#define MAX_SLOTS 5120    // 40 tiles * 128 rows

typedef unsigned short u16;
typedef unsigned int   u32;
typedef __bf16 bf16_t;
typedef bf16_t bf16x8 __attribute__((ext_vector_type(8)));
typedef u16    u16x8  __attribute__((ext_vector_type(8)));
typedef float  f32x4  __attribute__((ext_vector_type(4)));

#define MFMA __builtin_amdgcn_mfma_f32_16x16x32_bf16

__device__ __forceinline__ u16 bfbits(float f) {
    bf16_t b = (bf16_t)f;
    return __builtin_bit_cast(u16, b);
}

// swizzled LDS offset (u16 elems) for transposed B tile: row n (0..127), k-block kb (0..7)
__device__ __forceinline__ int bt_off(int n, int kb) {
    return n * 72 + ((kb ^ ((n >> 2) & 7)) << 3);
}

// ---------------- router: logits -> top2 -> normalized weights -> expert lists
__global__ __launch_bounds__(64) void router_k(
    const float* __restrict__ x, const float* __restrict__ rw,
    int* __restrict__ cnt, int* __restrict__ tok, float* __restrict__ wts,
    u16* __restrict__ xbf)
{
    int t = blockIdx.x;
    int lane = threadIdx.x;
    const float* xr = x + (size_t)t * H_DIM;
    u16* xbr = xbf + (size_t)t * H_DIM;

    float acc[E_N];
#pragma unroll
    for (int e = 0; e < E_N; e++) acc[e] = 0.f;
    for (int j = 0; j < H_DIM / 64; j++) {
        float xv = xr[lane + 64 * j];
        xbr[lane + 64 * j] = bfbits(xv);
#pragma unroll
        for (int e = 0; e < E_N; e++)
            acc[e] += xv * rw[e * H_DIM + lane + 64 * j];
    }
#pragma unroll
    for (int e = 0; e < E_N; e++) {
        float v = acc[e];
        for (int off = 32; off; off >>= 1) v += __shfl_xor(v, off);
        acc[e] = v;
    }
    if (lane == 0) {
        int i0 = 0; float m0 = acc[0];
#pragma unroll
        for (int e = 1; e < E_N; e++) if (acc[e] > m0) { m0 = acc[e]; i0 = e; }
        int i1 = -1; float m1 = -INFINITY;
#pragma unroll
        for (int e = 0; e < E_N; e++) if (e != i0 && acc[e] > m1) { m1 = acc[e]; i1 = e; }
        float w0 = 1.f / (1.f + expf(m1 - m0));
        float w1 = 1.f - w0;
        int p0 = atomicAdd(&cnt[i0], 1);
        tok[i0 * T_TOK + p0] = t; wts[i0 * T_TOK + p0] = w0;
        int p1 = atomicAdd(&cnt[i1], 1);
        tok[i1 * T_TOK + p1] = t; wts[i1 * T_TOK + p1] = w1;
    }
}

// ---------------- prefix + padded tile map (BM=128)
__global__ void prefix_k(const int* __restrict__ cnt, int* __restrict__ offs_pad,
                         int* __restrict__ tile_e, int* __restrict__ tile_row0,
                         int* __restrict__ ntiles)
{
    if (threadIdx.x == 0) {
        int s = 0, nt = 0;
        for (int e = 0; e < E_N; e++) {
            offs_pad[e] = s;
            int c = cnt[e];
            int t = (c + 127) >> 7;
            for (int i = 0; i < t; i++) { tile_e[nt] = e; tile_row0[nt] = i * 128; nt++; }
            s += t * 128;
        }
        offs_pad[E_N] = s;
        *ntiles = nt;
    }
}

// ---------------- gate/up grouped GEMM: act[slot][i] = silu(x@wg)*(x@wu)
// tile 128x128, BK=64, 4 waves (2Mx2N), dbuf LDS.
// Pipeline order per iter: barrier -> issue v(k+1) -> MFMA(k) -> cvt v -> LDS(buf^1).
// Nothing in the VMEM queue at barrier time (syncthreads drains vmcnt(0)).
__global__ __launch_bounds__(256, 2) void gateup_k(
    const u16* __restrict__ xbf, const float* __restrict__ wg, const float* __restrict__ wu,
    const int* __restrict__ cnt, const int* __restrict__ offs_pad,
    const int* __restrict__ tile_e, const int* __restrict__ tile_row0,
    const int* __restrict__ ntiles, const int* __restrict__ tok,
    u16* __restrict__ act)
{
    int q = gridDim.x >> 3;
    int phys = blockIdx.x;
    int logical = (phys & 7) * q + (phys >> 3);
    int tb = logical % NT_MAX;
    int n0 = (logical / NT_MAX) * 128;
    if (tb >= *ntiles) return;
    int e = tile_e[tb], row0 = tile_row0[tb];
    int cntE = cnt[e];
    int slot0 = offs_pad[e] + row0;

    __shared__ u16 BT[2][2][128 * 72];   // [buf][mat][n][k] 72 KB

    int tid = threadIdx.x;
    int lane = tid & 63, wid = tid >> 6;
    int wm = wid >> 1, wn = wid & 1;
    int l15 = lane & 15, lg = lane >> 4;

    const u16* arow[4];
#pragma unroll
    for (int mf = 0; mf < 4; mf++) {
        int rr = row0 + wm * 64 + mf * 16 + l15;
        int rc = rr < cntE ? rr : cntE - 1;
        arow[mf] = xbf + (size_t)tok[e * T_TOK + rc] * H_DIM;
    }

    int nq = tid & 31;            // n-quad: cols sn..sn+3
    int kb = tid >> 5;            // k-block: rows kb*8..kb*8+7
    int sn = nq * 4;

    const float* gptr = wg + ((size_t)e * H_DIM + kb * 8) * I_DIM + n0 + sn;
    const float* uptr = wu + ((size_t)e * H_DIM + kb * 8) * I_DIM + n0 + sn;

    float4 vg[8], vu[8];
#pragma unroll
    for (int i = 0; i < 8; i++) {
        vg[i] = *reinterpret_cast<const float4*>(gptr + (size_t)i * I_DIM);
        vu[i] = *reinterpret_cast<const float4*>(uptr + (size_t)i * I_DIM);
    }
    // prologue: stage k0=0 into buf 0
#pragma unroll
    for (int c = 0; c < 4; c++) {
        u16x8 pg, pu;
#pragma unroll
        for (int i = 0; i < 8; i++) {
            float fg = (c == 0) ? vg[i].x : (c == 1) ? vg[i].y : (c == 2) ? vg[i].z : vg[i].w;
            float fu = (c == 0) ? vu[i].x : (c == 1) ? vu[i].y : (c == 2) ? vu[i].z : vu[i].w;
            pg[i] = bfbits(fg); pu[i] = bfbits(fu);
        }
        *reinterpret_cast<u16x8*>(&BT[0][0][bt_off(sn + c, kb)]) = pg;
        *reinterpret_cast<u16x8*>(&BT[0][1][bt_off(sn + c, kb)]) = pu;
    }

    f32x4 accg[4][4], accu[4][4];
#pragma unroll
    for (int a = 0; a < 4; a++)
#pragma unroll
        for (int b = 0; b < 4; b++) { accg[a][b] = (f32x4)0.f; accu[a][b] = (f32x4)0.f; }

#pragma unroll 2
    for (int k0 = 0; k0 < H_DIM; k0 += 64) {
        int buf = (k0 >> 6) & 1;
        bool more = (k0 + 64) < H_DIM;

        __syncthreads();   // BT[buf] visible; VMEM queue is empty here

        // issue next weight tile's loads (in flight across the MFMA cluster)
        if (more) {
#pragma unroll
            for (int i = 0; i < 8; i++) {
                vg[i] = *reinterpret_cast<const float4*>(gptr + (size_t)(k0 + 64 + i) * I_DIM);
                vu[i] = *reinterpret_cast<const float4*>(uptr + (size_t)(k0 + 64 + i) * I_DIM);
            }
        }

        // MFMA cluster on BT[buf] (+ A fragments direct from L2/L3-resident xbf)
#pragma unroll
        for (int ks = 0; ks < 2; ks++) {
            bf16x8 af[4];
#pragma unroll
            for (int mf = 0; mf < 4; mf++)
                af[mf] = *reinterpret_cast<const bf16x8*>(arow[mf] + k0 + ks * 32 + lg * 8);
            int kbr = ks * 4 + lg;
#pragma unroll
            for (int nf = 0; nf < 4; nf++) {
                int c = wn * 64 + nf * 16 + l15;
                bf16x8 bg = *reinterpret_cast<const bf16x8*>(&BT[buf][0][bt_off(c, kbr)]);
                bf16x8 bu = *reinterpret_cast<const bf16x8*>(&BT[buf][1][bt_off(c, kbr)]);
#pragma unroll
                for (int mf = 0; mf < 4; mf++) {
                    accg[mf][nf] = MFMA(af[mf], bg, accg[mf][nf], 0, 0, 0);
                    accu[mf][nf] = MFMA(af[mf], bu, accu[mf][nf], 0, 0, 0);
                }
            }
        }

        // tail: convert the (now-arrived) next tile into the other buffer
        if (more) {
#pragma unroll
            for (int c = 0; c < 4; c++) {
                u16x8 pg, pu;
#pragma unroll
                for (int i = 0; i < 8; i++) {
                    float fg = (c == 0) ? vg[i].x : (c == 1) ? vg[i].y : (c == 2) ? vg[i].z : vg[i].w;
                    float fu = (c == 0) ? vu[i].x : (c == 1) ? vu[i].y : (c == 2) ? vu[i].z : vu[i].w;
                    pg[i] = bfbits(fg); pu[i] = bfbits(fu);
                }
                *reinterpret_cast<u16x8*>(&BT[buf ^ 1][0][bt_off(sn + c, kb)]) = pg;
                *reinterpret_cast<u16x8*>(&BT[buf ^ 1][1][bt_off(sn + c, kb)]) = pu;
            }
        }
    }

    // epilogue: silu(g)*u -> bf16; padded rows -> 0 (down_k reads them)
#pragma unroll
    for (int mf = 0; mf < 4; mf++)
#pragma unroll
        for (int j = 0; j < 4; j++) {
            int rl = wm * 64 + mf * 16 + lg * 4 + j;
            bool valid = (row0 + rl) < cntE;
            size_t base = (size_t)(slot0 + rl) * I_DIM + n0;
#pragma unroll
            for (int nf = 0; nf < 4; nf++) {
                float g = accg[mf][nf][j];
                float u = accu[mf][nf][j];
                float a = valid ? (g / (1.f + expf(-g))) * u : 0.f;
                act[base + wn * 64 + nf * 16 + l15] = bfbits(a);
            }
        }
}

// ---------------- down grouped GEMM: out[t] += w * (act @ w_down[e])
// tile 128x128, K split in 2 halves of 1024, same pipeline order, dbuf LDS 36 KB.
__global__ __launch_bounds__(256, 3) void down_k(
    const u16* __restrict__ act, const float* __restrict__ wd,
    const int* __restrict__ cnt, const int* __restrict__ offs_pad,
    const int* __restrict__ tile_e, const int* __restrict__ tile_row0,
    const int* __restrict__ ntiles, const int* __restrict__ tok,
    const float* __restrict__ wts, float* __restrict__ out)
{
    int q = gridDim.x >> 3;
    int phys = blockIdx.x;
    int logical = (phys & 7) * q + (phys >> 3);
    int tb = logical % NT_MAX;
    int rest = logical / NT_MAX;
    int h0 = (rest & 7) * 128;
    int kh = rest >> 3;                 // K half: 0 or 1
    if (tb >= *ntiles) return;
    int e = tile_e[tb], row0 = tile_row0[tb];
    int cntE = cnt[e];
    int slot0 = offs_pad[e] + row0;

    __shared__ u16 BT[2][128 * 72];

    int tid = threadIdx.x;
    int lane = tid & 63, wid = tid >> 6;
    int wm = wid >> 1, wn = wid & 1;
    int l15 = lane & 15, lg = lane >> 4;

    const u16* arow[4];
#pragma unroll
    for (int mf = 0; mf < 4; mf++)
        arow[mf] = act + (size_t)(slot0 + wm * 64 + mf * 16 + l15) * I_DIM + kh * 1024;

    int kb = tid >> 5;                  // k-chunk (8 rows)
    int sn = (tid & 31) * 4;            // 4 cols

    const float* dptr = wd + ((size_t)e * I_DIM + kh * 1024 + kb * 8) * H_DIM + h0 + sn;

    float4 v[8];
#pragma unroll
    for (int i = 0; i < 8; i++)
        v[i] = *reinterpret_cast<const float4*>(dptr + (size_t)i * H_DIM);
#pragma unroll
    for (int c = 0; c < 4; c++) {
        u16x8 p;
#pragma unroll
        for (int i = 0; i < 8; i++) {
            float f = (c == 0) ? v[i].x : (c == 1) ? v[i].y : (c == 2) ? v[i].z : v[i].w;
            p[i] = bfbits(f);
        }
        *reinterpret_cast<u16x8*>(&BT[0][bt_off(sn + c, kb)]) = p;
    }

    f32x4 acc[4][4];
#pragma unroll
    for (int a = 0; a < 4; a++)
#pragma unroll
        for (int b = 0; b < 4; b++) acc[a][b] = (f32x4)0.f;

#pragma unroll 2
    for (int k0 = 0; k0 < 1024; k0 += 64) {
        int buf = (k0 >> 6) & 1;
        bool more = (k0 + 64) < 1024;

        __syncthreads();

        if (more) {
#pragma unroll
            for (int i = 0; i < 8; i++)
                v[i] = *reinterpret_cast<const float4*>(dptr + (size_t)(k0 + 64 + i) * H_DIM);
        }

#pragma unroll
        for (int ks = 0; ks < 2; ks++) {
            bf16x8 af[4];
#pragma unroll
            for (int mf = 0; mf < 4; mf++)
                af[mf] = *reinterpret_cast<const bf16x8*>(arow[mf] + k0 + ks * 32 + lg * 8);
            int kbr = ks * 4 + lg;
#pragma unroll
            for (int nf = 0; nf < 4; nf++) {
                int c = wn * 64 + nf * 16 + l15;
                bf16x8 bfr = *reinterpret_cast<const bf16x8*>(&BT[buf][bt_off(c, kbr)]);
#pragma unroll
                for (int mf = 0; mf < 4; mf++)
                    acc[mf][nf] = MFMA(af[mf], bfr, acc[mf][nf], 0, 0, 0);
            }
        }

        if (more) {
#pragma unroll
            for (int c = 0; c < 4; c++) {
                u16x8 p;
#pragma unroll
                for (int i = 0; i < 8; i++) {
                    float f = (c == 0) ? v[i].x : (c == 1) ? v[i].y : (c == 2) ? v[i].z : v[i].w;
                    p[i] = bfbits(f);
                }
                *reinterpret_cast<u16x8*>(&BT[buf ^ 1][bt_off(sn + c, kb)]) = p;
            }
        }
    }

#pragma unroll
    for (int mf = 0; mf < 4; mf++)
#pragma unroll
        for (int j = 0; j < 4; j++) {
            int rl = wm * 64 + mf * 16 + lg * 4 + j;
            int gr = row0 + rl;
            if (gr < cntE) {
                float w = wts[e * T_TOK + gr];
                int t   = tok[e * T_TOK + gr];
                size_t base = (size_t)t * H_DIM + h0;
#pragma unroll
                for (int nf = 0; nf < 4; nf++)
                    atomicAdd(&out[base + wn * 64 + nf * 16 + l15], acc[mf][nf][j] * w);
            }
        }
}

extern "C" void kernel_launch(void* const* d_in, const int* in_sizes, int n_in,
                              void* d_out, int out_size, void* d_ws, size_t ws_size,
                              hipStream_t stream)
{
    const float* x  = (const float*)d_in[0];
    const float* rw = (const float*)d_in[1];
    const float* wg = (const float*)d_in[2];
    const float* wu = (const float*)d_in[3];
    const float* wd = (const float*)d_in[4];
    float* out = (float*)d_out;

    char* ws = (char*)d_ws;
    int*   cnt       = (int*)(ws);                 // 8 ints
    int*   ntiles    = (int*)(ws + 32);
    int*   offs_pad  = (int*)(ws + 64);            // 9 ints
    int*   tile_e    = (int*)(ws + 256);           // NT_MAX ints
    int*   tile_row0 = (int*)(ws + 512);           // NT_MAX ints
    int*   tok       = (int*)(ws + 64 * 1024);     // E*T ints (64 KB)
    float* wts       = (float*)(ws + 128 * 1024);  // 64 KB
    u16*   xbf       = (u16*)(ws + 256 * 1024);    // 4 MB
    u16*   act       = (u16*)(ws + 4608 * 1024);   // 5120*2048*2 = 21 MB

    size_t need = 4608ull * 1024 + (size_t)MAX_SLOTS * I_DIM * 2;
    if (ws_size < need) return;

    hipMemsetAsync(cnt, 0, 32, stream);
    hipMemsetAsync(out, 0, (size_t)T_TOK * H_DIM * sizeof(float), stream);

    router_k<<<T_TOK, 64, 0, stream>>>(x, rw, cnt, tok, wts, xbf);
    prefix_k<<<1, 64, 0, stream>>>(cnt, offs_pad, tile_e, tile_row0, ntiles);
    gateup_k<<<NT_MAX * (I_DIM / 128), 256, 0, stream>>>(
        xbf, wg, wu, cnt, offs_pad, tile_e, tile_row0, ntiles, tok, act);
    down_k<<<NT_MAX * (H_DIM / 128) * 2, 256, 0, stream>>>(
        act, wd, cnt, offs_pad, tile_e, tile_row0, ntiles, tok, wts, out);
}

// Round 6
// 274.565 us; speedup vs baseline: 1.1628x; 1.1628x over previous
//
#include <hip/hip_runtime.h>
#include <hip/hip_bf16.h>

#define T_TOK 2048
#define H_DIM 1024
#define E_N   8
#define I_DIM 2048

#define NT_MAX 40         // sum ceil(cnt_e/128) <= 4096/128 + 7 = 39
#define MAX_SLOTS 5120    // 40 tiles * 128 rows

typedef unsigned short u16;
typedef unsigned int   u32;
typedef __bf16 bf16_t;
typedef bf16_t bf16x8 __attribute__((ext_vector_type(8)));
typedef u16    u16x8  __attribute__((ext_vector_type(8)));
typedef float  f32x4  __attribute__((ext_vector_type(4)));

#define MFMA __builtin_amdgcn_mfma_f32_16x16x32_bf16

__device__ __forceinline__ u16 bfbits(float f) {
    bf16_t b = (bf16_t)f;
    return __builtin_bit_cast(u16, b);
}

__device__ __forceinline__ void gload_lds16(const void* g, void* l) {
    __builtin_amdgcn_global_load_lds(
        (const __attribute__((address_space(1))) void*)g,
        (__attribute__((address_space(3))) void*)l, 16, 0, 0);
}

// in-tile u16 offset for pre-swizzled bf16 weight tiles: col n (0..127), k (0..63)
// 8 consecutive k per 16B group; group slot XOR'd by (n>>1)&7 -> 2-way banks on b128 read
__device__ __forceinline__ int tile_off(int n, int kb) {   // kb = k>>3
    return n * 64 + ((kb ^ ((n >> 1) & 7)) << 3);
}

// legacy swizzled offset for fallback path (row stride 72)
__device__ __forceinline__ int bt_off(int n, int kb) {
    return n * 72 + ((kb ^ ((n >> 2) & 7)) << 3);
}

// ---------------- router: logits -> top2 -> normalized weights -> expert lists
__global__ __launch_bounds__(64) void router_k(
    const float* __restrict__ x, const float* __restrict__ rw,
    int* __restrict__ cnt, int* __restrict__ tok, float* __restrict__ wts,
    u16* __restrict__ xbf)
{
    int t = blockIdx.x;
    int lane = threadIdx.x;
    const float* xr = x + (size_t)t * H_DIM;
    u16* xbr = xbf + (size_t)t * H_DIM;

    float acc[E_N];
#pragma unroll
    for (int e = 0; e < E_N; e++) acc[e] = 0.f;
    for (int j = 0; j < H_DIM / 64; j++) {
        float xv = xr[lane + 64 * j];
        xbr[lane + 64 * j] = bfbits(xv);
#pragma unroll
        for (int e = 0; e < E_N; e++)
            acc[e] += xv * rw[e * H_DIM + lane + 64 * j];
    }
#pragma unroll
    for (int e = 0; e < E_N; e++) {
        float v = acc[e];
        for (int off = 32; off; off >>= 1) v += __shfl_xor(v, off);
        acc[e] = v;
    }
    if (lane == 0) {
        int i0 = 0; float m0 = acc[0];
#pragma unroll
        for (int e = 1; e < E_N; e++) if (acc[e] > m0) { m0 = acc[e]; i0 = e; }
        int i1 = -1; float m1 = -INFINITY;
#pragma unroll
        for (int e = 0; e < E_N; e++) if (e != i0 && acc[e] > m1) { m1 = acc[e]; i1 = e; }
        float w0 = 1.f / (1.f + expf(m1 - m0));
        float w1 = 1.f - w0;
        int p0 = atomicAdd(&cnt[i0], 1);
        tok[i0 * T_TOK + p0] = t; wts[i0 * T_TOK + p0] = w0;
        int p1 = atomicAdd(&cnt[i1], 1);
        tok[i1 * T_TOK + p1] = t; wts[i1 * T_TOK + p1] = w1;
    }
}

// ---------------- prefix + padded tile map (BM=128)
__global__ void prefix_k(const int* __restrict__ cnt, int* __restrict__ offs_pad,
                         int* __restrict__ tile_e, int* __restrict__ tile_row0,
                         int* __restrict__ ntiles)
{
    if (threadIdx.x == 0) {
        int s = 0, nt = 0;
        for (int e = 0; e < E_N; e++) {
            offs_pad[e] = s;
            int c = cnt[e];
            int t = (c + 127) >> 7;
            for (int i = 0; i < t; i++) { tile_e[nt] = e; tile_row0[nt] = i * 128; nt++; }
            s += t * 128;
        }
        offs_pad[E_N] = s;
        *ntiles = nt;
    }
}

// ---------------- weight pre-convert: fp32 -> bf16, pre-swizzled 16KB tiles
// gate/up: tile ti = ((e*16+p)*16+b): cols p*128.., k-rows b*64.. of w[e][H][I]
// down:    tile ti = ((e*8+p)*32+b):  cols p*128.., k-rows b*64.. of wd[e][I][H]
__global__ __launch_bounds__(256) void cvtw_k(
    const float* __restrict__ wg, const float* __restrict__ wu, const float* __restrict__ wd,
    u16* __restrict__ tg, u16* __restrict__ tu, u16* __restrict__ td)
{
    __shared__ float S[64][132];
    int bid = blockIdx.x;
    int kind = bid >> 11;          // 0=gate 1=up 2=down
    int ti = bid & 2047;
    const float* src; u16* dst; int nstr;
    if (kind < 2) {
        const float* w = kind ? wu : wg;
        int e = ti >> 8, b = ti & 15;
        int p = (ti >> 4) & 15;
        src = w + ((size_t)e * H_DIM + b * 64) * I_DIM + p * 128;
        nstr = I_DIM;
        dst = (kind ? tu : tg) + (size_t)ti * 8192;
    } else {
        int e = ti >> 8, r = ti & 255;
        int p = r >> 5, b = r & 31;
        src = wd + ((size_t)e * I_DIM + b * 64) * H_DIM + p * 128;
        nstr = H_DIM;
        dst = td + (size_t)ti * 8192;
    }
    int t = threadIdx.x;
#pragma unroll
    for (int i = 0; i < 8; i++) {
        int idx = t + i * 256;                 // float4 index in 64x128 tile
        int k = idx >> 5, c4 = idx & 31;
        float4 v = *reinterpret_cast<const float4*>(src + (size_t)k * nstr + c4 * 4);
        *reinterpret_cast<float4*>(&S[k][c4 * 4]) = v;
    }
    __syncthreads();
#pragma unroll
    for (int i = 0; i < 4; i++) {
        int oidx = t + i * 256;                // u16x8 index: 128n x 8kb
        int n = oidx & 127, kb = oidx >> 7;
        u16x8 pk;
#pragma unroll
        for (int j = 0; j < 8; j++) pk[j] = bfbits(S[kb * 8 + j][n]);
        *reinterpret_cast<u16x8*>(dst + tile_off(n, kb)) = pk;
    }
}

// ---------------- PATH A gate/up GEMM: global_load_lds staged bf16 tiles
__global__ __launch_bounds__(256, 2) void gateupA_k(
    const u16* __restrict__ xbf, const u16* __restrict__ tg, const u16* __restrict__ tu,
    const int* __restrict__ cnt, const int* __restrict__ offs_pad,
    const int* __restrict__ tile_e, const int* __restrict__ tile_row0,
    const int* __restrict__ ntiles, const int* __restrict__ tok,
    u16* __restrict__ act)
{
    int q = gridDim.x >> 3;
    int phys = blockIdx.x;
    int logical = (phys & 7) * q + (phys >> 3);
    int tb = logical % NT_MAX;
    int p  = logical / NT_MAX;             // n-panel 0..15
    if (tb >= *ntiles) return;
    int e = tile_e[tb], row0 = tile_row0[tb];
    int cntE = cnt[e];
    int slot0 = offs_pad[e] + row0;
    int n0 = p * 128;

    __shared__ u16 BT[2][2][8192];         // [buf][mat] 64 KB total

    int tid = threadIdx.x;
    int lane = tid & 63, wid = tid >> 6;
    int wm = wid >> 1, wn = wid & 1;
    int l15 = lane & 15, lg = lane >> 4;

    const u16* arow[4];
#pragma unroll
    for (int mf = 0; mf < 4; mf++) {
        int rr = row0 + wm * 64 + mf * 16 + l15;
        int rc = rr < cntE ? rr : cntE - 1;
        arow[mf] = xbf + (size_t)tok[e * T_TOK + rc] * H_DIM;
    }

    const u16* tgB = tg + ((size_t)(e * 16 + p) * 16) * 8192;
    const u16* tuB = tu + ((size_t)(e * 16 + p) * 16) * 8192;

#define STAGE_GU(bufi, b) { \
    const u16* gG = tgB + (size_t)(b) * 8192; \
    const u16* gU = tuB + (size_t)(b) * 8192; \
    _Pragma("unroll") \
    for (int i_ = 0; i_ < 4; i_++) { \
        int ub = i_ * 256 + wid * 64; \
        gload_lds16(gG + (ub + lane) * 8, &BT[bufi][0][ub * 8]); \
        gload_lds16(gU + (ub + lane) * 8, &BT[bufi][1][ub * 8]); \
    } }

    f32x4 accg[4][4], accu[4][4];
#pragma unroll
    for (int a = 0; a < 4; a++)
#pragma unroll
        for (int b = 0; b < 4; b++) { accg[a][b] = (f32x4)0.f; accu[a][b] = (f32x4)0.f; }

    STAGE_GU(0, 0);
    __syncthreads();                       // drains prologue loads (vmcnt 0)

    for (int b = 0; b < 16; b++) {         // 16 k-blocks of 64
        int buf = b & 1;
        if (b + 1 < 16) STAGE_GU(buf ^ 1, b + 1);

#pragma unroll
        for (int ks = 0; ks < 2; ks++) {
            bf16x8 af[4];
#pragma unroll
            for (int mf = 0; mf < 4; mf++)
                af[mf] = *reinterpret_cast<const bf16x8*>(arow[mf] + b * 64 + ks * 32 + lg * 8);
            int kbr = ks * 4 + lg;
#pragma unroll
            for (int nf = 0; nf < 4; nf++) {
                int c = wn * 64 + nf * 16 + l15;
                int o = tile_off(c, kbr);
                bf16x8 bg = *reinterpret_cast<const bf16x8*>(&BT[buf][0][o]);
                bf16x8 bu = *reinterpret_cast<const bf16x8*>(&BT[buf][1][o]);
#pragma unroll
                for (int mf = 0; mf < 4; mf++) {
                    accg[mf][nf] = MFMA(af[mf], bg, accg[mf][nf], 0, 0, 0);
                    accu[mf][nf] = MFMA(af[mf], bu, accu[mf][nf], 0, 0, 0);
                }
            }
        }
        __syncthreads();                   // drains STAGE(buf^1); orders BT[buf] reuse
    }

#pragma unroll
    for (int mf = 0; mf < 4; mf++)
#pragma unroll
        for (int j = 0; j < 4; j++) {
            int rl = wm * 64 + mf * 16 + lg * 4 + j;
            bool valid = (row0 + rl) < cntE;
            size_t base = (size_t)(slot0 + rl) * I_DIM + n0;
#pragma unroll
            for (int nf = 0; nf < 4; nf++) {
                float g = accg[mf][nf][j];
                float u = accu[mf][nf][j];
                float a = valid ? (g / (1.f + expf(-g))) * u : 0.f;
                act[base + wn * 64 + nf * 16 + l15] = bfbits(a);
            }
        }
#undef STAGE_GU
}

// ---------------- PATH A down GEMM: K split in 2, global_load_lds staged tiles
__global__ __launch_bounds__(256, 3) void downA_k(
    const u16* __restrict__ act, const u16* __restrict__ td,
    const int* __restrict__ cnt, const int* __restrict__ offs_pad,
    const int* __restrict__ tile_e, const int* __restrict__ tile_row0,
    const int* __restrict__ ntiles, const int* __restrict__ tok,
    const float* __restrict__ wts, float* __restrict__ out)
{
    int q = gridDim.x >> 3;
    int phys = blockIdx.x;
    int logical = (phys & 7) * q + (phys >> 3);
    int tb = logical % NT_MAX;
    int rest = logical / NT_MAX;
    int p  = rest & 7;                     // h-panel 0..7
    int kh = rest >> 3;                    // K half
    if (tb >= *ntiles) return;
    int e = tile_e[tb], row0 = tile_row0[tb];
    int cntE = cnt[e];
    int slot0 = offs_pad[e] + row0;
    int h0 = p * 128;

    __shared__ u16 BT[2][8192];            // 32 KB

    int tid = threadIdx.x;
    int lane = tid & 63, wid = tid >> 6;
    int wm = wid >> 1, wn = wid & 1;
    int l15 = lane & 15, lg = lane >> 4;

    const u16* arow[4];
#pragma unroll
    for (int mf = 0; mf < 4; mf++)
        arow[mf] = act + (size_t)(slot0 + wm * 64 + mf * 16 + l15) * I_DIM + kh * 1024;

    const u16* tdB = td + ((size_t)(e * 8 + p) * 32 + kh * 16) * 8192;

#define STAGE_D(bufi, b) { \
    const u16* gD = tdB + (size_t)(b) * 8192; \
    _Pragma("unroll") \
    for (int i_ = 0; i_ < 4; i_++) { \
        int ub = i_ * 256 + wid * 64; \
        gload_lds16(gD + (ub + lane) * 8, &BT[bufi][ub * 8]); \
    } }

    f32x4 acc[4][4];
#pragma unroll
    for (int a = 0; a < 4; a++)
#pragma unroll
        for (int b = 0; b < 4; b++) acc[a][b] = (f32x4)0.f;

    STAGE_D(0, 0);
    __syncthreads();

    for (int b = 0; b < 16; b++) {         // 16 k-blocks of 64 (one K half)
        int buf = b & 1;
        if (b + 1 < 16) STAGE_D(buf ^ 1, b + 1);

#pragma unroll
        for (int ks = 0; ks < 2; ks++) {
            bf16x8 af[4];
#pragma unroll
            for (int mf = 0; mf < 4; mf++)
                af[mf] = *reinterpret_cast<const bf16x8*>(arow[mf] + b * 64 + ks * 32 + lg * 8);
            int kbr = ks * 4 + lg;
#pragma unroll
            for (int nf = 0; nf < 4; nf++) {
                int c = wn * 64 + nf * 16 + l15;
                bf16x8 bd = *reinterpret_cast<const bf16x8*>(&BT[buf][tile_off(c, kbr)]);
#pragma unroll
                for (int mf = 0; mf < 4; mf++)
                    acc[mf][nf] = MFMA(af[mf], bd, acc[mf][nf], 0, 0, 0);
            }
        }
        __syncthreads();
    }

#pragma unroll
    for (int mf = 0; mf < 4; mf++)
#pragma unroll
        for (int j = 0; j < 4; j++) {
            int rl = wm * 64 + mf * 16 + lg * 4 + j;
            int gr = row0 + rl;
            if (gr < cntE) {
                float w = wts[e * T_TOK + gr];
                int t   = tok[e * T_TOK + gr];
                size_t base = (size_t)t * H_DIM + h0;
#pragma unroll
                for (int nf = 0; nf < 4; nf++)
                    atomicAdd(&out[base + wn * 64 + nf * 16 + l15], acc[mf][nf][j] * w);
            }
        }
#undef STAGE_D
}

// ================= PATH B (fallback, small ws): round-3 kernels =================
__global__ __launch_bounds__(256, 2) void gateupB_k(
    const u16* __restrict__ xbf, const float* __restrict__ wg, const float* __restrict__ wu,
    const int* __restrict__ cnt, const int* __restrict__ offs_pad,
    const int* __restrict__ tile_e, const int* __restrict__ tile_row0,
    const int* __restrict__ ntiles, const int* __restrict__ tok,
    u16* __restrict__ act)
{
    int q = gridDim.x >> 3;
    int phys = blockIdx.x;
    int logical = (phys & 7) * q + (phys >> 3);
    int tb = logical % NT_MAX;
    int n0 = (logical / NT_MAX) * 128;
    if (tb >= *ntiles) return;
    int e = tile_e[tb], row0 = tile_row0[tb];
    int cntE = cnt[e];
    int slot0 = offs_pad[e] + row0;

    __shared__ u16 BT[2][2][128 * 72];

    int tid = threadIdx.x;
    int lane = tid & 63, wid = tid >> 6;
    int wm = wid >> 1, wn = wid & 1;
    int l15 = lane & 15, lg = lane >> 4;

    const u16* arow[4];
#pragma unroll
    for (int mf = 0; mf < 4; mf++) {
        int rr = row0 + wm * 64 + mf * 16 + l15;
        int rc = rr < cntE ? rr : cntE - 1;
        arow[mf] = xbf + (size_t)tok[e * T_TOK + rc] * H_DIM;
    }

    int nq = tid & 31;
    int kb = tid >> 5;
    int sn = nq * 4;

    const float* gptr = wg + ((size_t)e * H_DIM + kb * 8) * I_DIM + n0 + sn;
    const float* uptr = wu + ((size_t)e * H_DIM + kb * 8) * I_DIM + n0 + sn;

    float4 vg[8], vu[8];
#pragma unroll
    for (int i = 0; i < 8; i++) {
        vg[i] = *reinterpret_cast<const float4*>(gptr + (size_t)i * I_DIM);
        vu[i] = *reinterpret_cast<const float4*>(uptr + (size_t)i * I_DIM);
    }

    f32x4 accg[4][4], accu[4][4];
#pragma unroll
    for (int a = 0; a < 4; a++)
#pragma unroll
        for (int b = 0; b < 4; b++) { accg[a][b] = (f32x4)0.f; accu[a][b] = (f32x4)0.f; }

    for (int k0 = 0; k0 < H_DIM; k0 += 64) {
        int buf = (k0 >> 6) & 1;
#pragma unroll
        for (int c = 0; c < 4; c++) {
            u16x8 pg, pu;
#pragma unroll
            for (int i = 0; i < 8; i++) {
                float fg = (c == 0) ? vg[i].x : (c == 1) ? vg[i].y : (c == 2) ? vg[i].z : vg[i].w;
                float fu = (c == 0) ? vu[i].x : (c == 1) ? vu[i].y : (c == 2) ? vu[i].z : vu[i].w;
                pg[i] = bfbits(fg); pu[i] = bfbits(fu);
            }
            *reinterpret_cast<u16x8*>(&BT[buf][0][bt_off(sn + c, kb)]) = pg;
            *reinterpret_cast<u16x8*>(&BT[buf][1][bt_off(sn + c, kb)]) = pu;
        }
        if (k0 + 64 < H_DIM) {
#pragma unroll
            for (int i = 0; i < 8; i++) {
                vg[i] = *reinterpret_cast<const float4*>(gptr + (size_t)(k0 + 64 + i) * I_DIM);
                vu[i] = *reinterpret_cast<const float4*>(uptr + (size_t)(k0 + 64 + i) * I_DIM);
            }
        }
        __syncthreads();

#pragma unroll
        for (int ks = 0; ks < 2; ks++) {
            bf16x8 af[4];
#pragma unroll
            for (int mf = 0; mf < 4; mf++)
                af[mf] = *reinterpret_cast<const bf16x8*>(arow[mf] + k0 + ks * 32 + lg * 8);
            int kbr = ks * 4 + lg;
#pragma unroll
            for (int nf = 0; nf < 4; nf++) {
                int c = wn * 64 + nf * 16 + l15;
                bf16x8 bg = *reinterpret_cast<const bf16x8*>(&BT[buf][0][bt_off(c, kbr)]);
                bf16x8 bu = *reinterpret_cast<const bf16x8*>(&BT[buf][1][bt_off(c, kbr)]);
#pragma unroll
                for (int mf = 0; mf < 4; mf++) {
                    accg[mf][nf] = MFMA(af[mf], bg, accg[mf][nf], 0, 0, 0);
                    accu[mf][nf] = MFMA(af[mf], bu, accu[mf][nf], 0, 0, 0);
                }
            }
        }
    }

#pragma unroll
    for (int mf = 0; mf < 4; mf++)
#pragma unroll
        for (int j = 0; j < 4; j++) {
            int rl = wm * 64 + mf * 16 + lg * 4 + j;
            bool valid = (row0 + rl) < cntE;
            size_t base = (size_t)(slot0 + rl) * I_DIM + n0;
#pragma unroll
            for (int nf = 0; nf < 4; nf++) {
                float g = accg[mf][nf][j];
                float u = accu[mf][nf][j];
                float a = valid ? (g / (1.f + expf(-g))) * u : 0.f;
                act[base + wn * 64 + nf * 16 + l15] = bfbits(a);
            }
        }
}

__global__ __launch_bounds__(256, 2) void downB_k(
    const u16* __restrict__ act, const float* __restrict__ wd,
    const int* __restrict__ cnt, const int* __restrict__ offs_pad,
    const int* __restrict__ tile_e, const int* __restrict__ tile_row0,
    const int* __restrict__ ntiles, const int* __restrict__ tok,
    const float* __restrict__ wts, float* __restrict__ out)
{
    int q = gridDim.x >> 3;
    int phys = blockIdx.x;
    int logical = (phys & 7) * q + (phys >> 3);
    int tb = logical % NT_MAX;
    int h0 = (logical / NT_MAX) * 128;
    if (tb >= *ntiles) return;
    int e = tile_e[tb], row0 = tile_row0[tb];
    int cntE = cnt[e];
    int slot0 = offs_pad[e] + row0;

    __shared__ u16 BT[2][128 * 72];

    int tid = threadIdx.x;
    int lane = tid & 63, wid = tid >> 6;
    int wm = wid >> 1, wn = wid & 1;
    int l15 = lane & 15, lg = lane >> 4;

    const u16* arow[4];
#pragma unroll
    for (int mf = 0; mf < 4; mf++)
        arow[mf] = act + (size_t)(slot0 + wm * 64 + mf * 16 + l15) * I_DIM;

    int kb = tid >> 5;
    int sn = (tid & 31) * 4;

    const float* dptr = wd + ((size_t)e * I_DIM + kb * 8) * H_DIM + h0 + sn;

    float4 v[8];
#pragma unroll
    for (int i = 0; i < 8; i++)
        v[i] = *reinterpret_cast<const float4*>(dptr + (size_t)i * H_DIM);

    f32x4 acc[4][4];
#pragma unroll
    for (int a = 0; a < 4; a++)
#pragma unroll
        for (int b = 0; b < 4; b++) acc[a][b] = (f32x4)0.f;

    for (int k0 = 0; k0 < I_DIM; k0 += 64) {
        int buf = (k0 >> 6) & 1;
#pragma unroll
        for (int c = 0; c < 4; c++) {
            u16x8 p;
#pragma unroll
            for (int i = 0; i < 8; i++) {
                float f = (c == 0) ? v[i].x : (c == 1) ? v[i].y : (c == 2) ? v[i].z : v[i].w;
                p[i] = bfbits(f);
            }
            *reinterpret_cast<u16x8*>(&BT[buf][bt_off(sn + c, kb)]) = p;
        }
        if (k0 + 64 < I_DIM) {
#pragma unroll
            for (int i = 0; i < 8; i++)
                v[i] = *reinterpret_cast<const float4*>(dptr + (size_t)(k0 + 64 + i) * H_DIM);
        }
        __syncthreads();

#pragma unroll
        for (int ks = 0; ks < 2; ks++) {
            bf16x8 af[4];
#pragma unroll
            for (int mf = 0; mf < 4; mf++)
                af[mf] = *reinterpret_cast<const bf16x8*>(arow[mf] + k0 + ks * 32 + lg * 8);
            int kbr = ks * 4 + lg;
#pragma unroll
            for (int nf = 0; nf < 4; nf++) {
                int c = wn * 64 + nf * 16 + l15;
                bf16x8 bfr = *reinterpret_cast<const bf16x8*>(&BT[buf][bt_off(c, kbr)]);
#pragma unroll
                for (int mf = 0; mf < 4; mf++)
                    acc[mf][nf] = MFMA(af[mf], bfr, acc[mf][nf], 0, 0, 0);
            }
        }
    }

#pragma unroll
    for (int mf = 0; mf < 4; mf++)
#pragma unroll
        for (int j = 0; j < 4; j++) {
            int rl = wm * 64 + mf * 16 + lg * 4 + j;
            int gr = row0 + rl;
            if (gr < cntE) {
                float w = wts[e * T_TOK + gr];
                int t   = tok[e * T_TOK + gr];
                size_t base = (size_t)t * H_DIM + h0;
#pragma unroll
                for (int nf = 0; nf < 4; nf++)
                    atomicAdd(&out[base + wn * 64 + nf * 16 + l15], acc[mf][nf][j] * w);
            }
        }
}

extern "C" void kernel_launch(void* const* d_in, const int* in_sizes, int n_in,
                              void* d_out, int out_size, void* d_ws, size_t ws_size,
                              hipStream_t stream)
{
    const float* x  = (const float*)d_in[0];
    const float* rw = (const float*)d_in[1];
    const float* wg = (const float*)d_in[2];
    const float* wu = (const float*)d_in[3];
    const float* wd = (const float*)d_in[4];
    float* out = (float*)d_out;

    char* ws = (char*)d_ws;
    int*   cnt       = (int*)(ws);
    int*   ntiles    = (int*)(ws + 32);
    int*   offs_pad  = (int*)(ws + 64);
    int*   tile_e    = (int*)(ws + 256);
    int*   tile_row0 = (int*)(ws + 512);
    int*   tok       = (int*)(ws + 64 * 1024);
    float* wts       = (float*)(ws + 128 * 1024);
    u16*   xbf       = (u16*)(ws + 256 * 1024);
    u16*   act       = (u16*)(ws + 4608 * 1024);   // 21 MB

    const size_t OFF_TG = 28ull << 20;             // after act
    const size_t TSZ    = 2048ull * 16384;         // 32 MiB per tensor
    u16* tg = (u16*)(ws + OFF_TG);
    u16* tu = (u16*)(ws + OFF_TG + TSZ);
    u16* td = (u16*)(ws + OFF_TG + 2 * TSZ);

    size_t need_b = 4608ull * 1024 + (size_t)MAX_SLOTS * I_DIM * 2;
    size_t need_a = OFF_TG + 3 * TSZ;
    if (ws_size < need_b) return;
    bool big = ws_size >= need_a;

    hipMemsetAsync(cnt, 0, 32, stream);
    hipMemsetAsync(out, 0, (size_t)T_TOK * H_DIM * sizeof(float), stream);

    router_k<<<T_TOK, 64, 0, stream>>>(x, rw, cnt, tok, wts, xbf);
    prefix_k<<<1, 64, 0, stream>>>(cnt, offs_pad, tile_e, tile_row0, ntiles);

    if (big) {
        cvtw_k<<<3 * 2048, 256, 0, stream>>>(wg, wu, wd, tg, tu, td);
        gateupA_k<<<NT_MAX * (I_DIM / 128), 256, 0, stream>>>(
            xbf, tg, tu, cnt, offs_pad, tile_e, tile_row0, ntiles, tok, act);
        downA_k<<<NT_MAX * (H_DIM / 128) * 2, 256, 0, stream>>>(
            act, td, cnt, offs_pad, tile_e, tile_row0, ntiles, tok, wts, out);
    } else {
        gateupB_k<<<NT_MAX * (I_DIM / 128), 256, 0, stream>>>(
            xbf, wg, wu, cnt, offs_pad, tile_e, tile_row0, ntiles, tok, act);
        downB_k<<<NT_MAX * (H_DIM / 128), 256, 0, stream>>>(
            act, wd, cnt, offs_pad, tile_e, tile_row0, ntiles, tok, wts, out);
    }
}

// Round 7
// 238.736 us; speedup vs baseline: 1.3373x; 1.1501x over previous
//
#include <hip/hip_runtime.h>
#include <hip/hip_bf16.h>

#define T_TOK 2048
#define H_DIM 1024
#define E_N   8
#define I_DIM 2048

#define NT_MAX 40         // sum ceil(cnt_e/128) <= 4096/128 + 7 = 39
#define MAX_SLOTS 5120    // 40 tiles * 128 rows

typedef unsigned short u16;
typedef unsigned int   u32;
typedef __bf16 bf16_t;
typedef bf16_t bf16x8 __attribute__((ext_vector_type(8)));
typedef u16    u16x8  __attribute__((ext_vector_type(8)));
typedef float  f32x4  __attribute__((ext_vector_type(4)));

#define MFMA __builtin_amdgcn_mfma_f32_16x16x32_bf16

__device__ __forceinline__ u16 bfbits(float f) {
    bf16_t b = (bf16_t)f;
    return __builtin_bit_cast(u16, b);
}

__device__ __forceinline__ void gload_lds16(const void* g, void* l) {
    __builtin_amdgcn_global_load_lds(
        (const __attribute__((address_space(1))) void*)g,
        (__attribute__((address_space(3))) void*)l, 16, 0, 0);
}

// B tiles (pre-swizzled at cvt time): col n (0..127), kslot kb (0..7): u16 idx
__device__ __forceinline__ int tile_off(int n, int kb) {
    return n * 64 + ((kb ^ ((n >> 1) & 7)) << 3);
}
// A LDS tile (linear gload_lds dest, source pre-XOR'd): row (0..127), kslot (0..7)
__device__ __forceinline__ int a_off(int row, int kslot) {
    return row * 64 + ((kslot ^ (row & 7)) << 3);
}

// ---------------- fused: weight fp32->bf16 pre-swizzled tiles  +  router
__global__ __launch_bounds__(256) void prep_k(
    const float* __restrict__ x, const float* __restrict__ rw,
    const float* __restrict__ wg, const float* __restrict__ wu, const float* __restrict__ wd,
    u16* __restrict__ tg, u16* __restrict__ tu, u16* __restrict__ td,
    int* __restrict__ cnt, int* __restrict__ tok, float* __restrict__ wts,
    u16* __restrict__ xbf)
{
    __shared__ float S[64][132];
    int bid = blockIdx.x;

    if (bid >= 6144) {
        // ---- router: 4 tokens per block, one wave each ----
        int wid = threadIdx.x >> 6, lane = threadIdx.x & 63;
        int t = (bid - 6144) * 4 + wid;
        const float* xr = x + (size_t)t * H_DIM;
        u16* xbr = xbf + (size_t)t * H_DIM;
        float acc[E_N];
#pragma unroll
        for (int e = 0; e < E_N; e++) acc[e] = 0.f;
        for (int j = 0; j < H_DIM / 64; j++) {
            float xv = xr[lane + 64 * j];
            xbr[lane + 64 * j] = bfbits(xv);
#pragma unroll
            for (int e = 0; e < E_N; e++)
                acc[e] += xv * rw[e * H_DIM + lane + 64 * j];
        }
#pragma unroll
        for (int e = 0; e < E_N; e++) {
            float v = acc[e];
            for (int off = 32; off; off >>= 1) v += __shfl_xor(v, off);
            acc[e] = v;
        }
        if (lane == 0) {
            int i0 = 0; float m0 = acc[0];
#pragma unroll
            for (int e = 1; e < E_N; e++) if (acc[e] > m0) { m0 = acc[e]; i0 = e; }
            int i1 = -1; float m1 = -INFINITY;
#pragma unroll
            for (int e = 0; e < E_N; e++) if (e != i0 && acc[e] > m1) { m1 = acc[e]; i1 = e; }
            float w0 = 1.f / (1.f + expf(m1 - m0));
            float w1 = 1.f - w0;
            int p0 = atomicAdd(&cnt[i0], 1);
            tok[i0 * T_TOK + p0] = t; wts[i0 * T_TOK + p0] = w0;
            int p1 = atomicAdd(&cnt[i1], 1);
            tok[i1 * T_TOK + p1] = t; wts[i1 * T_TOK + p1] = w1;
        }
        return;
    }

    // ---- weight tile convert ----
    int kind = bid >> 11;          // 0=gate 1=up 2=down
    int ti = bid & 2047;
    const float* src; u16* dst; int nstr;
    if (kind < 2) {
        const float* w = kind ? wu : wg;
        int e = ti >> 8, b = ti & 15;
        int p = (ti >> 4) & 15;
        src = w + ((size_t)e * H_DIM + b * 64) * I_DIM + p * 128;
        nstr = I_DIM;
        dst = (kind ? tu : tg) + (size_t)ti * 8192;
    } else {
        int e = ti >> 8, r = ti & 255;
        int p = r >> 5, b = r & 31;
        src = wd + ((size_t)e * I_DIM + b * 64) * H_DIM + p * 128;
        nstr = H_DIM;
        dst = td + (size_t)ti * 8192;
    }
    int tid = threadIdx.x;
#pragma unroll
    for (int i = 0; i < 8; i++) {
        int idx = tid + i * 256;
        int k = idx >> 5, c4 = idx & 31;
        float4 v = *reinterpret_cast<const float4*>(src + (size_t)k * nstr + c4 * 4);
        *reinterpret_cast<float4*>(&S[k][c4 * 4]) = v;
    }
    __syncthreads();
#pragma unroll
    for (int i = 0; i < 4; i++) {
        int oidx = tid + i * 256;
        int n = oidx & 127, kb = oidx >> 7;
        u16x8 pk;
#pragma unroll
        for (int j = 0; j < 8; j++) pk[j] = bfbits(S[kb * 8 + j][n]);
        *reinterpret_cast<u16x8*>(dst + tile_off(n, kb)) = pk;
    }
}

// ---------------- prefix + padded tile map (BM=128)
__global__ void prefix_k(const int* __restrict__ cnt, int* __restrict__ offs_pad,
                         int* __restrict__ tile_e, int* __restrict__ tile_row0,
                         int* __restrict__ ntiles)
{
    if (threadIdx.x == 0) {
        int s = 0, nt = 0;
        for (int e = 0; e < E_N; e++) {
            offs_pad[e] = s;
            int c = cnt[e];
            int t = (c + 127) >> 7;
            for (int i = 0; i < t; i++) { tile_e[nt] = e; tile_row0[nt] = i * 128; nt++; }
            s += t * 128;
        }
        offs_pad[E_N] = s;
        *ntiles = nt;
    }
}

// ---------------- gate/up grouped GEMM: all-LDS staging, counted vmcnt, no drain
// tile 128x128, BK=64, 8 waves (4M x 2N), wave tile 32x64 per matrix
__global__ __launch_bounds__(512, 2) void gateup_k(
    const u16* __restrict__ xbf, const u16* __restrict__ tg, const u16* __restrict__ tu,
    const int* __restrict__ cnt, const int* __restrict__ offs_pad,
    const int* __restrict__ tile_e, const int* __restrict__ tile_row0,
    const int* __restrict__ ntiles, const int* __restrict__ tok,
    u16* __restrict__ act)
{
    int q = gridDim.x >> 3;
    int phys = blockIdx.x;
    int logical = (phys & 7) * q + (phys >> 3);
    int tb = logical % NT_MAX;
    int p  = logical / NT_MAX;
    if (tb >= *ntiles) return;
    int e = tile_e[tb], row0 = tile_row0[tb];
    int cntE = cnt[e];
    int slot0 = offs_pad[e] + row0;
    int n0 = p * 128;

    __shared__ u16 AS[2][8192], GS[2][8192], US[2][8192];   // 96 KB

    int tid = threadIdx.x;
    int lane = tid & 63, wid = tid >> 6;
    int wm = wid & 3, wn = wid >> 2;
    int l15 = lane & 15, lg = lane >> 4;

    // A staging sources: instr ai=wid*2+i covers rows ai*8..ai*8+7; lane -> row ai*8+(lane>>3),
    // source k-group pre-XOR'd so the linear LDS write realizes the a_off swizzle.
    const u16* asrc[2];
#pragma unroll
    for (int i = 0; i < 2; i++) {
        int row = (wid * 2 + i) * 8 + (lane >> 3);
        int rc = (row0 + row < cntE) ? (row0 + row) : (cntE - 1);
        asrc[i] = xbf + (size_t)tok[e * T_TOK + rc] * H_DIM + (((lane & 7) ^ (lane >> 3)) << 3);
    }
    const u16* tgB = tg + ((size_t)(e * 16 + p) * 16) * 8192;
    const u16* tuB = tu + ((size_t)(e * 16 + p) * 16) * 8192;
    int s0 = (wid * 2) * 512;        // u16 base of this wave's first staging chunk

#define STAGE_GU(bufi, t) { \
    gload_lds16(asrc[0] + (size_t)(t) * 64, &AS[bufi][s0]); \
    gload_lds16(asrc[1] + (size_t)(t) * 64, &AS[bufi][s0 + 512]); \
    gload_lds16(tgB + (size_t)(t) * 8192 + s0 + lane * 8,       &GS[bufi][s0]); \
    gload_lds16(tgB + (size_t)(t) * 8192 + s0 + 512 + lane * 8, &GS[bufi][s0 + 512]); \
    gload_lds16(tuB + (size_t)(t) * 8192 + s0 + lane * 8,       &US[bufi][s0]); \
    gload_lds16(tuB + (size_t)(t) * 8192 + s0 + 512 + lane * 8, &US[bufi][s0 + 512]); }

    f32x4 accg[2][4], accu[2][4];
#pragma unroll
    for (int a = 0; a < 2; a++)
#pragma unroll
        for (int b = 0; b < 4; b++) { accg[a][b] = (f32x4)0.f; accu[a][b] = (f32x4)0.f; }

    STAGE_GU(0, 0);                    // 6 loads in flight

    for (int t = 0; t < 16; t++) {
        int buf = t & 1;
        if (t + 1 < 16) {
            STAGE_GU(buf ^ 1, t + 1);                       // 12 in flight
            asm volatile("s_waitcnt vmcnt(6)" ::: "memory"); // tile t landed, t+1 in flight
        } else {
            asm volatile("s_waitcnt vmcnt(0)" ::: "memory");
        }
        __builtin_amdgcn_s_barrier();
        __builtin_amdgcn_sched_barrier(0);

#pragma unroll
        for (int ks = 0; ks < 2; ks++) {
            bf16x8 af[2];
#pragma unroll
            for (int mf = 0; mf < 2; mf++) {
                int row = wm * 32 + mf * 16 + l15;
                af[mf] = *reinterpret_cast<const bf16x8*>(&AS[buf][a_off(row, ks * 4 + lg)]);
            }
            int kbr = ks * 4 + lg;
#pragma unroll
            for (int nf = 0; nf < 4; nf++) {
                int c = wn * 64 + nf * 16 + l15;
                int o = tile_off(c, kbr);
                bf16x8 bg = *reinterpret_cast<const bf16x8*>(&GS[buf][o]);
                bf16x8 bu = *reinterpret_cast<const bf16x8*>(&US[buf][o]);
#pragma unroll
                for (int mf = 0; mf < 2; mf++) {
                    accg[mf][nf] = MFMA(af[mf], bg, accg[mf][nf], 0, 0, 0);
                    accu[mf][nf] = MFMA(af[mf], bu, accu[mf][nf], 0, 0, 0);
                }
            }
        }
        __builtin_amdgcn_s_barrier();        // readers done before next STAGE overwrites
        __builtin_amdgcn_sched_barrier(0);
    }
#undef STAGE_GU

    // epilogue: silu(g)*u -> bf16; padded rows -> 0 (down_k reads them)
#pragma unroll
    for (int mf = 0; mf < 2; mf++)
#pragma unroll
        for (int j = 0; j < 4; j++) {
            int rl = wm * 32 + mf * 16 + lg * 4 + j;
            bool valid = (row0 + rl) < cntE;
            size_t base = (size_t)(slot0 + rl) * I_DIM + n0;
#pragma unroll
            for (int nf = 0; nf < 4; nf++) {
                float g = accg[mf][nf][j];
                float u = accu[mf][nf][j];
                float a = valid ? (g / (1.f + expf(-g))) * u : 0.f;
                act[base + wn * 64 + nf * 16 + l15] = bfbits(a);
            }
        }
}

// ---------------- down grouped GEMM: same pipeline, K split in 2 halves
__global__ __launch_bounds__(512, 4) void down_k(
    const u16* __restrict__ act, const u16* __restrict__ td,
    const int* __restrict__ cnt, const int* __restrict__ offs_pad,
    const int* __restrict__ tile_e, const int* __restrict__ tile_row0,
    const int* __restrict__ ntiles, const int* __restrict__ tok,
    const float* __restrict__ wts, float* __restrict__ out)
{
    int q = gridDim.x >> 3;
    int phys = blockIdx.x;
    int logical = (phys & 7) * q + (phys >> 3);
    int tb = logical % NT_MAX;
    int rest = logical / NT_MAX;
    int p  = rest & 7;
    int kh = rest >> 3;
    if (tb >= *ntiles) return;
    int e = tile_e[tb], row0 = tile_row0[tb];
    int cntE = cnt[e];
    int slot0 = offs_pad[e] + row0;
    int h0 = p * 128;

    __shared__ u16 AS[2][8192], DS[2][8192];    // 64 KB -> 2 blocks/CU

    int tid = threadIdx.x;
    int lane = tid & 63, wid = tid >> 6;
    int wm = wid & 3, wn = wid >> 2;
    int l15 = lane & 15, lg = lane >> 4;

    const u16* asrc[2];
#pragma unroll
    for (int i = 0; i < 2; i++) {
        int row = (wid * 2 + i) * 8 + (lane >> 3);
        asrc[i] = act + (size_t)(slot0 + row) * I_DIM + kh * 1024
                  + (((lane & 7) ^ (lane >> 3)) << 3);
    }
    const u16* tdB = td + ((size_t)(e * 8 + p) * 32 + kh * 16) * 8192;
    int s0 = (wid * 2) * 512;

#define STAGE_D(bufi, t) { \
    gload_lds16(asrc[0] + (size_t)(t) * 64, &AS[bufi][s0]); \
    gload_lds16(asrc[1] + (size_t)(t) * 64, &AS[bufi][s0 + 512]); \
    gload_lds16(tdB + (size_t)(t) * 8192 + s0 + lane * 8,       &DS[bufi][s0]); \
    gload_lds16(tdB + (size_t)(t) * 8192 + s0 + 512 + lane * 8, &DS[bufi][s0 + 512]); }

    f32x4 acc[2][4];
#pragma unroll
    for (int a = 0; a < 2; a++)
#pragma unroll
        for (int b = 0; b < 4; b++) acc[a][b] = (f32x4)0.f;

    STAGE_D(0, 0);

    for (int t = 0; t < 16; t++) {
        int buf = t & 1;
        if (t + 1 < 16) {
            STAGE_D(buf ^ 1, t + 1);
            asm volatile("s_waitcnt vmcnt(4)" ::: "memory");
        } else {
            asm volatile("s_waitcnt vmcnt(0)" ::: "memory");
        }
        __builtin_amdgcn_s_barrier();
        __builtin_amdgcn_sched_barrier(0);

#pragma unroll
        for (int ks = 0; ks < 2; ks++) {
            bf16x8 af[2];
#pragma unroll
            for (int mf = 0; mf < 2; mf++) {
                int row = wm * 32 + mf * 16 + l15;
                af[mf] = *reinterpret_cast<const bf16x8*>(&AS[buf][a_off(row, ks * 4 + lg)]);
            }
            int kbr = ks * 4 + lg;
#pragma unroll
            for (int nf = 0; nf < 4; nf++) {
                int c = wn * 64 + nf * 16 + l15;
                bf16x8 bd = *reinterpret_cast<const bf16x8*>(&DS[buf][tile_off(c, kbr)]);
#pragma unroll
                for (int mf = 0; mf < 2; mf++)
                    acc[mf][nf] = MFMA(af[mf], bd, acc[mf][nf], 0, 0, 0);
            }
        }
        __builtin_amdgcn_s_barrier();
        __builtin_amdgcn_sched_barrier(0);
    }
#undef STAGE_D

#pragma unroll
    for (int mf = 0; mf < 2; mf++)
#pragma unroll
        for (int j = 0; j < 4; j++) {
            int rl = wm * 32 + mf * 16 + lg * 4 + j;
            int gr = row0 + rl;
            if (gr < cntE) {
                float w = wts[e * T_TOK + gr];
                int t   = tok[e * T_TOK + gr];
                size_t base = (size_t)t * H_DIM + h0;
#pragma unroll
                for (int nf = 0; nf < 4; nf++)
                    atomicAdd(&out[base + wn * 64 + nf * 16 + l15], acc[mf][nf][j] * w);
            }
        }
}

extern "C" void kernel_launch(void* const* d_in, const int* in_sizes, int n_in,
                              void* d_out, int out_size, void* d_ws, size_t ws_size,
                              hipStream_t stream)
{
    const float* x  = (const float*)d_in[0];
    const float* rw = (const float*)d_in[1];
    const float* wg = (const float*)d_in[2];
    const float* wu = (const float*)d_in[3];
    const float* wd = (const float*)d_in[4];
    float* out = (float*)d_out;

    char* ws = (char*)d_ws;
    int*   cnt       = (int*)(ws);
    int*   ntiles    = (int*)(ws + 32);
    int*   offs_pad  = (int*)(ws + 64);
    int*   tile_e    = (int*)(ws + 256);
    int*   tile_row0 = (int*)(ws + 512);
    int*   tok       = (int*)(ws + 64 * 1024);
    float* wts       = (float*)(ws + 128 * 1024);
    u16*   xbf       = (u16*)(ws + 256 * 1024);    // 4 MB
    u16*   act       = (u16*)(ws + 4608 * 1024);   // 21 MB

    const size_t OFF_TG = 28ull << 20;
    const size_t TSZ    = 2048ull * 16384;         // 32 MiB per tensor
    u16* tg = (u16*)(ws + OFF_TG);
    u16* tu = (u16*)(ws + OFF_TG + TSZ);
    u16* td = (u16*)(ws + OFF_TG + 2 * TSZ);

    size_t need = OFF_TG + 3 * TSZ;
    if (ws_size < need) return;

    hipMemsetAsync(cnt, 0, 32, stream);
    hipMemsetAsync(out, 0, (size_t)T_TOK * H_DIM * sizeof(float), stream);

    prep_k<<<6144 + T_TOK / 4, 256, 0, stream>>>(x, rw, wg, wu, wd, tg, tu, td,
                                                 cnt, tok, wts, xbf);
    prefix_k<<<1, 64, 0, stream>>>(cnt, offs_pad, tile_e, tile_row0, ntiles);
    gateup_k<<<NT_MAX * (I_DIM / 128), 512, 0, stream>>>(
        xbf, tg, tu, cnt, offs_pad, tile_e, tile_row0, ntiles, tok, act);
    down_k<<<NT_MAX * (H_DIM / 128) * 2, 512, 0, stream>>>(
        act, td, cnt, offs_pad, tile_e, tile_row0, ntiles, tok, wts, out);
}

// Round 8
// 218.089 us; speedup vs baseline: 1.4639x; 1.0947x over previous
//
#include <hip/hip_runtime.h>
#include <hip/hip_bf16.h>

#define T_TOK 2048
#define H_DIM 1024
#define E_N   8
#define I_DIM 2048

#define NT_MAX 40         // sum ceil(cnt_e/128) <= 4096/128 + 7 = 39
#define MAX_SLOTS 5120    // 40 tiles * 128 rows

typedef unsigned short u16;
typedef unsigned int   u32;
typedef __bf16 bf16_t;
typedef bf16_t bf16x8 __attribute__((ext_vector_type(8)));
typedef u16    u16x8  __attribute__((ext_vector_type(8)));
typedef float  f32x4  __attribute__((ext_vector_type(4)));

#define MFMA __builtin_amdgcn_mfma_f32_16x16x32_bf16

__device__ __forceinline__ u16 bfbits(float f) {
    bf16_t b = (bf16_t)f;
    return __builtin_bit_cast(u16, b);
}

__device__ __forceinline__ void gload_lds16(const void* g, void* l) {
    __builtin_amdgcn_global_load_lds(
        (const __attribute__((address_space(1))) void*)g,
        (__attribute__((address_space(3))) void*)l, 16, 0, 0);
}

// B LDS tile: col n (0..127), k-slot kb (0..7); XOR by (n>>1)&7:
// writes (stride-128B column writes) and reads (16-consecutive-n row reads)
// both land at ~2-way bank aliasing (free).
__device__ __forceinline__ int tile_off(int n, int kb) {
    return n * 64 + ((kb ^ ((n >> 1) & 7)) << 3);
}
// A LDS tile (linear gload_lds dest, source k-group pre-XOR'd): row, kslot
__device__ __forceinline__ int a_off(int row, int kslot) {
    return row * 64 + ((kslot ^ (row & 7)) << 3);
}

// ---------------- router: 4 tokens/block; logits -> top2 -> weights -> lists
__global__ __launch_bounds__(256) void router_k(
    const float* __restrict__ x, const float* __restrict__ rw,
    int* __restrict__ cnt, int* __restrict__ tok, float* __restrict__ wts,
    u16* __restrict__ xbf)
{
    int wid = threadIdx.x >> 6, lane = threadIdx.x & 63;
    int t = blockIdx.x * 4 + wid;
    const float* xr = x + (size_t)t * H_DIM;
    u16* xbr = xbf + (size_t)t * H_DIM;

    float acc[E_N];
#pragma unroll
    for (int e = 0; e < E_N; e++) acc[e] = 0.f;
    for (int j = 0; j < H_DIM / 64; j++) {
        float xv = xr[lane + 64 * j];
        xbr[lane + 64 * j] = bfbits(xv);
#pragma unroll
        for (int e = 0; e < E_N; e++)
            acc[e] += xv * rw[e * H_DIM + lane + 64 * j];
    }
#pragma unroll
    for (int e = 0; e < E_N; e++) {
        float v = acc[e];
        for (int off = 32; off; off >>= 1) v += __shfl_xor(v, off);
        acc[e] = v;
    }
    if (lane == 0) {
        int i0 = 0; float m0 = acc[0];
#pragma unroll
        for (int e = 1; e < E_N; e++) if (acc[e] > m0) { m0 = acc[e]; i0 = e; }
        int i1 = -1; float m1 = -INFINITY;
#pragma unroll
        for (int e = 0; e < E_N; e++) if (e != i0 && acc[e] > m1) { m1 = acc[e]; i1 = e; }
        float w0 = 1.f / (1.f + expf(m1 - m0));
        float w1 = 1.f - w0;
        int p0 = atomicAdd(&cnt[i0], 1);
        tok[i0 * T_TOK + p0] = t; wts[i0 * T_TOK + p0] = w0;
        int p1 = atomicAdd(&cnt[i1], 1);
        tok[i1 * T_TOK + p1] = t; wts[i1 * T_TOK + p1] = w1;
    }
}

// ---------------- prefix + padded tile map (BM=128)
__global__ void prefix_k(const int* __restrict__ cnt, int* __restrict__ offs_pad,
                         int* __restrict__ tile_e, int* __restrict__ tile_row0,
                         int* __restrict__ ntiles)
{
    if (threadIdx.x == 0) {
        int s = 0, nt = 0;
        for (int e = 0; e < E_N; e++) {
            offs_pad[e] = s;
            int c = cnt[e];
            int t = (c + 127) >> 7;
            for (int i = 0; i < t; i++) { tile_e[nt] = e; tile_row0[nt] = i * 128; nt++; }
            s += t * 128;
        }
        offs_pad[E_N] = s;
        *ntiles = nt;
    }
}

// ---------------- gate/up grouped GEMM, fused fp32->bf16 weight conversion
// tile 128x128, BK=64, 8 waves (4M x 2N). Per iter:
//   issue A gload_lds(t+1) + B column fp32 loads(t+1) -> MFMA(t) ->
//   cvt+ds_write B(t+1) -> __syncthreads()
__global__ __launch_bounds__(512, 2) void gateup_k(
    const u16* __restrict__ xbf, const float* __restrict__ wg, const float* __restrict__ wu,
    const int* __restrict__ cnt, const int* __restrict__ offs_pad,
    const int* __restrict__ tile_e, const int* __restrict__ tile_row0,
    const int* __restrict__ ntiles, const int* __restrict__ tok,
    u16* __restrict__ act)
{
    int q = gridDim.x >> 3;
    int phys = blockIdx.x;
    int logical = (phys & 7) * q + (phys >> 3);
    int tb = logical % NT_MAX;
    int p  = logical / NT_MAX;             // n-panel 0..15
    if (tb >= *ntiles) return;
    int e = tile_e[tb], row0 = tile_row0[tb];
    int cntE = cnt[e];
    int slot0 = offs_pad[e] + row0;
    int n0 = p * 128;

    __shared__ u16 AS[2][8192], GS[2][8192], US[2][8192];   // 96 KB

    int tid = threadIdx.x;
    int lane = tid & 63, wid = tid >> 6;
    int wm = wid & 3, wn = wid >> 2;
    int l15 = lane & 15, lg = lane >> 4;

    // ---- A staging sources (gathered token rows, k-group pre-XOR'd) ----
    const u16* asrc[2];
#pragma unroll
    for (int i = 0; i < 2; i++) {
        int row = (wid * 2 + i) * 8 + (lane >> 3);
        int rc = (row0 + row < cntE) ? (row0 + row) : (cntE - 1);
        asrc[i] = xbf + (size_t)tok[e * T_TOK + rc] * H_DIM + (((lane & 7) ^ (lane >> 3)) << 3);
    }
    int s0 = (wid * 2) * 512;

    // ---- B staging: one column per thread, 32 k's ----
    int mat   = tid >> 8;                  // 0: gate, 1: up
    int tid8  = tid & 255;
    int bn    = tid8 & 127;
    int khalf = tid8 >> 7;
    const float* wsrc = (mat ? wu : wg)
        + ((size_t)e * H_DIM + khalf * 32) * I_DIM + n0 + bn;

    float v[32];

#define B_LOAD(t) { \
    _Pragma("unroll") \
    for (int j = 0; j < 32; j++) \
        v[j] = wsrc[(size_t)((t) * 64 + j) * I_DIM]; }

#define B_WRITE(nbuf) { \
    u16* bdst = mat ? US[nbuf] : GS[nbuf]; \
    _Pragma("unroll") \
    for (int jb = 0; jb < 4; jb++) { \
        u16x8 pk; \
        _Pragma("unroll") \
        for (int jj = 0; jj < 8; jj++) pk[jj] = bfbits(v[jb * 8 + jj]); \
        *reinterpret_cast<u16x8*>(&bdst[tile_off(bn, khalf * 4 + jb)]) = pk; \
    } }

#define A_STAGE(nbuf, t) { \
    gload_lds16(asrc[0] + (size_t)(t) * 64, &AS[nbuf][s0]); \
    gload_lds16(asrc[1] + (size_t)(t) * 64, &AS[nbuf][s0 + 512]); }

    f32x4 accg[2][4], accu[2][4];
#pragma unroll
    for (int a = 0; a < 2; a++)
#pragma unroll
        for (int b = 0; b < 4; b++) { accg[a][b] = (f32x4)0.f; accu[a][b] = (f32x4)0.f; }

    // prologue: tile 0
    A_STAGE(0, 0);
    B_LOAD(0);
    B_WRITE(0);
    __syncthreads();

#pragma unroll 2
    for (int t = 0; t < 16; t++) {
        int buf = t & 1;
        bool more = (t + 1) < 16;
        if (more) {
            A_STAGE(buf ^ 1, t + 1);
            B_LOAD(t + 1);
        }
        __builtin_amdgcn_sched_barrier(0);   // loads stay issued above the MFMA cluster

#pragma unroll
        for (int ks = 0; ks < 2; ks++) {
            bf16x8 af[2];
#pragma unroll
            for (int mf = 0; mf < 2; mf++) {
                int row = wm * 32 + mf * 16 + l15;
                af[mf] = *reinterpret_cast<const bf16x8*>(&AS[buf][a_off(row, ks * 4 + lg)]);
            }
            int kbr = ks * 4 + lg;
#pragma unroll
            for (int nf = 0; nf < 4; nf++) {
                int c = wn * 64 + nf * 16 + l15;
                int o = tile_off(c, kbr);
                bf16x8 bg = *reinterpret_cast<const bf16x8*>(&GS[buf][o]);
                bf16x8 bu = *reinterpret_cast<const bf16x8*>(&US[buf][o]);
#pragma unroll
                for (int mf = 0; mf < 2; mf++) {
                    accg[mf][nf] = MFMA(af[mf], bg, accg[mf][nf], 0, 0, 0);
                    accu[mf][nf] = MFMA(af[mf], bu, accu[mf][nf], 0, 0, 0);
                }
            }
        }

        if (more) B_WRITE(buf ^ 1);          // vmcnt waits hidden under the cluster
        __syncthreads();
    }
#undef B_LOAD
#undef B_WRITE
#undef A_STAGE

    // epilogue: silu(g)*u -> bf16; padded rows -> 0 (down_k reads them)
#pragma unroll
    for (int mf = 0; mf < 2; mf++)
#pragma unroll
        for (int j = 0; j < 4; j++) {
            int rl = wm * 32 + mf * 16 + lg * 4 + j;
            bool valid = (row0 + rl) < cntE;
            size_t base = (size_t)(slot0 + rl) * I_DIM + n0;
#pragma unroll
            for (int nf = 0; nf < 4; nf++) {
                float g = accg[mf][nf][j];
                float u = accu[mf][nf][j];
                float a = valid ? (g / (1.f + expf(-g))) * u : 0.f;
                act[base + wn * 64 + nf * 16 + l15] = bfbits(a);
            }
        }
}

// ---------------- down grouped GEMM, fused conversion, K split in 2 halves
__global__ __launch_bounds__(512, 4) void down_k(
    const u16* __restrict__ act, const float* __restrict__ wd,
    const int* __restrict__ cnt, const int* __restrict__ offs_pad,
    const int* __restrict__ tile_e, const int* __restrict__ tile_row0,
    const int* __restrict__ ntiles, const int* __restrict__ tok,
    const float* __restrict__ wts, float* __restrict__ out)
{
    int q = gridDim.x >> 3;
    int phys = blockIdx.x;
    int logical = (phys & 7) * q + (phys >> 3);
    int tb = logical % NT_MAX;
    int rest = logical / NT_MAX;
    int p  = rest & 7;                     // h-panel 0..7
    int kh = rest >> 3;                    // K half
    if (tb >= *ntiles) return;
    int e = tile_e[tb], row0 = tile_row0[tb];
    int cntE = cnt[e];
    int slot0 = offs_pad[e] + row0;
    int h0 = p * 128;

    __shared__ u16 AS[2][8192], DS[2][8192];    // 64 KB -> 2 blocks/CU

    int tid = threadIdx.x;
    int lane = tid & 63, wid = tid >> 6;
    int wm = wid & 3, wn = wid >> 2;
    int l15 = lane & 15, lg = lane >> 4;

    const u16* asrc[2];
#pragma unroll
    for (int i = 0; i < 2; i++) {
        int row = (wid * 2 + i) * 8 + (lane >> 3);
        asrc[i] = act + (size_t)(slot0 + row) * I_DIM + kh * 1024
                  + (((lane & 7) ^ (lane >> 3)) << 3);
    }
    int s0 = (wid * 2) * 512;

    int bn = tid & 127;
    int kq = tid >> 7;                     // 0..3, 16 k's each
    const float* dsrc = wd + ((size_t)e * I_DIM + kh * 1024 + kq * 16) * H_DIM + h0 + bn;

    float v[16];

#define B_LOAD(t) { \
    _Pragma("unroll") \
    for (int j = 0; j < 16; j++) \
        v[j] = dsrc[(size_t)((t) * 64 + j) * H_DIM]; }

#define B_WRITE(nbuf) { \
    _Pragma("unroll") \
    for (int jb = 0; jb < 2; jb++) { \
        u16x8 pk; \
        _Pragma("unroll") \
        for (int jj = 0; jj < 8; jj++) pk[jj] = bfbits(v[jb * 8 + jj]); \
        *reinterpret_cast<u16x8*>(&DS[nbuf][tile_off(bn, kq * 2 + jb)]) = pk; \
    } }

#define A_STAGE(nbuf, t) { \
    gload_lds16(asrc[0] + (size_t)(t) * 64, &AS[nbuf][s0]); \
    gload_lds16(asrc[1] + (size_t)(t) * 64, &AS[nbuf][s0 + 512]); }

    f32x4 acc[2][4];
#pragma unroll
    for (int a = 0; a < 2; a++)
#pragma unroll
        for (int b = 0; b < 4; b++) acc[a][b] = (f32x4)0.f;

    A_STAGE(0, 0);
    B_LOAD(0);
    B_WRITE(0);
    __syncthreads();

#pragma unroll 2
    for (int t = 0; t < 16; t++) {
        int buf = t & 1;
        bool more = (t + 1) < 16;
        if (more) {
            A_STAGE(buf ^ 1, t + 1);
            B_LOAD(t + 1);
        }
        __builtin_amdgcn_sched_barrier(0);

#pragma unroll
        for (int ks = 0; ks < 2; ks++) {
            bf16x8 af[2];
#pragma unroll
            for (int mf = 0; mf < 2; mf++) {
                int row = wm * 32 + mf * 16 + l15;
                af[mf] = *reinterpret_cast<const bf16x8*>(&AS[buf][a_off(row, ks * 4 + lg)]);
            }
            int kbr = ks * 4 + lg;
#pragma unroll
            for (int nf = 0; nf < 4; nf++) {
                int c = wn * 64 + nf * 16 + l15;
                bf16x8 bd = *reinterpret_cast<const bf16x8*>(&DS[buf][tile_off(c, kbr)]);
#pragma unroll
                for (int mf = 0; mf < 2; mf++)
                    acc[mf][nf] = MFMA(af[mf], bd, acc[mf][nf], 0, 0, 0);
            }
        }

        if (more) B_WRITE(buf ^ 1);
        __syncthreads();
    }
#undef B_LOAD
#undef B_WRITE
#undef A_STAGE

#pragma unroll
    for (int mf = 0; mf < 2; mf++)
#pragma unroll
        for (int j = 0; j < 4; j++) {
            int rl = wm * 32 + mf * 16 + lg * 4 + j;
            int gr = row0 + rl;
            if (gr < cntE) {
                float w = wts[e * T_TOK + gr];
                int t   = tok[e * T_TOK + gr];
                size_t base = (size_t)t * H_DIM + h0;
#pragma unroll
                for (int nf = 0; nf < 4; nf++)
                    atomicAdd(&out[base + wn * 64 + nf * 16 + l15], acc[mf][nf][j] * w);
            }
        }
}

extern "C" void kernel_launch(void* const* d_in, const int* in_sizes, int n_in,
                              void* d_out, int out_size, void* d_ws, size_t ws_size,
                              hipStream_t stream)
{
    const float* x  = (const float*)d_in[0];
    const float* rw = (const float*)d_in[1];
    const float* wg = (const float*)d_in[2];
    const float* wu = (const float*)d_in[3];
    const float* wd = (const float*)d_in[4];
    float* out = (float*)d_out;

    char* ws = (char*)d_ws;
    int*   cnt       = (int*)(ws);
    int*   ntiles    = (int*)(ws + 32);
    int*   offs_pad  = (int*)(ws + 64);
    int*   tile_e    = (int*)(ws + 256);
    int*   tile_row0 = (int*)(ws + 512);
    int*   tok       = (int*)(ws + 64 * 1024);
    float* wts       = (float*)(ws + 128 * 1024);
    u16*   xbf       = (u16*)(ws + 256 * 1024);    // 4 MB
    u16*   act       = (u16*)(ws + 4608 * 1024);   // 5120*2048*2 = 20 MB

    size_t need = 4608ull * 1024 + (size_t)MAX_SLOTS * I_DIM * 2;
    if (ws_size < need) return;

    hipMemsetAsync(cnt, 0, 32, stream);
    hipMemsetAsync(out, 0, (size_t)T_TOK * H_DIM * sizeof(float), stream);

    router_k<<<T_TOK / 4, 256, 0, stream>>>(x, rw, cnt, tok, wts, xbf);
    prefix_k<<<1, 64, 0, stream>>>(cnt, offs_pad, tile_e, tile_row0, ntiles);
    gateup_k<<<NT_MAX * (I_DIM / 128), 512, 0, stream>>>(
        xbf, wg, wu, cnt, offs_pad, tile_e, tile_row0, ntiles, tok, act);
    down_k<<<NT_MAX * (H_DIM / 128) * 2, 512, 0, stream>>>(
        act, wd, cnt, offs_pad, tile_e, tile_row0, ntiles, tok, wts, out);
}